// Round 8
// baseline (150.000 us; speedup 1.0000x reference)
//
#include <hip/hip_runtime.h>
#include <stdint.h>

// out = dequant( int8(lhs*ls) @ int8(rhs*rs) ) / (ls*rs), 4096^3, fp32 in/out.
// ls = 127 / max(amax|lhs|, 1e-12). Int core is bit-exact vs numpy (RNE quant).
//
// Workspace: [0,16Mi) qA int8 MxK ; [16Mi,32Mi) qBT int8 NxK ; then 2x u32 amax bits.
//
// GEMM v7: MULTI-BLOCK overlap. All 256^2 variants (v2/v3/v6) ran 1 block/CU
// (128 KB LDS, 256 blocks on 256 CUs); in-block barriers lockstep the waves,
// so the LDS window and MFMA window serialize (every variant fit
// time = MFMA + LDS + const). The measured mechanism that overlaps the two
// pipes is co-resident INDEPENDENT blocks (m114: concurrent waves on one CU
// run at max, not sum -- it's why v1's naive 128^2/4-blocks-per-CU kernel
// held 91 us). v7 = small blocks + v6's schedule: 128x128 tile, BK=64,
// 4 waves (wave-tile 64x64, acc 64 regs), 32 KiB double-buffered LDS,
// prefetch-1, ONE barrier/window, launch_bounds(256,4) -> 4 blocks/CU
// (16 waves/CU). Per CU round: MFMA 1306 cyc vs LDS ~1536 cyc, overlapped
// across blocks instead of summed within one. Frag reads conflict-free via
// the v2-verified 64B-row pre-swizzle: LDS row (4 quads) position p holds
// global quad (p - (row>>1)) & 3; frag for quad q reads (q + (row>>1)) & 3.

#define NROW 4096
#define NELEM (4096 * 4096)

typedef __attribute__((ext_vector_type(4))) int int32x4;
typedef const __attribute__((address_space(1))) int8_t* gptr1_t;
typedef __attribute__((address_space(3))) int8_t* lptr3_t;

__global__ void absmax_both_kernel(const float* __restrict__ lhs,
                                   const float* __restrict__ rhs,
                                   unsigned* __restrict__ amax) {
    __shared__ float red[4];
    const int t = blockIdx.x & 1;
    const float4* x4 = (const float4*)(t ? rhs : lhs);
    const int bid = blockIdx.x >> 1;
    const int stride = (gridDim.x >> 1) * blockDim.x;  // 262144
    int i = bid * blockDim.x + threadIdx.x;
    float m0 = 0.0f, m1 = 0.0f, m2 = 0.0f, m3 = 0.0f;
    for (; i + 3 * stride < NELEM / 4; i += 4 * stride) {
        float4 a = x4[i];
        float4 b = x4[i + stride];
        float4 c = x4[i + 2 * stride];
        float4 d = x4[i + 3 * stride];
        m0 = fmaxf(m0, fmaxf(fmaxf(fabsf(a.x), fabsf(a.y)),
                             fmaxf(fabsf(a.z), fabsf(a.w))));
        m1 = fmaxf(m1, fmaxf(fmaxf(fabsf(b.x), fabsf(b.y)),
                             fmaxf(fabsf(b.z), fabsf(b.w))));
        m2 = fmaxf(m2, fmaxf(fmaxf(fabsf(c.x), fabsf(c.y)),
                             fmaxf(fabsf(c.z), fabsf(c.w))));
        m3 = fmaxf(m3, fmaxf(fmaxf(fabsf(d.x), fabsf(d.y)),
                             fmaxf(fabsf(d.z), fabsf(d.w))));
    }
    for (; i < NELEM / 4; i += stride) {
        float4 a = x4[i];
        m0 = fmaxf(m0, fmaxf(fmaxf(fabsf(a.x), fabsf(a.y)),
                             fmaxf(fabsf(a.z), fabsf(a.w))));
    }
    float m = fmaxf(fmaxf(m0, m1), fmaxf(m2, m3));
    for (int off = 32; off > 0; off >>= 1)
        m = fmaxf(m, __shfl_down(m, off, 64));
    const int lane = threadIdx.x & 63, wave = threadIdx.x >> 6;
    if (lane == 0) red[wave] = m;
    __syncthreads();
    if (threadIdx.x == 0) {
        float b = fmaxf(fmaxf(red[0], red[1]), fmaxf(red[2], red[3]));
        atomicMax(amax + t, __float_as_uint(b));  // |x|>=0: bits monotone as uint
    }
}

__device__ __forceinline__ int q8(float v, float s) {
    int r = __float2int_rn(v * s);  // RNE, matches jnp.round
    r = r < -127 ? -127 : r;
    r = r > 127 ? 127 : r;
    return r;
}

__global__ void quant_kernel(const float* __restrict__ lhs,
                             const float* __restrict__ rhs,
                             int8_t* __restrict__ qA, int8_t* __restrict__ qT,
                             const unsigned* __restrict__ amax) {
    __shared__ int8_t sm[64][68];
    if (blockIdx.x < 16384) {
        const float s = 127.0f / fmaxf(__uint_as_float(amax[0]), 1e-12f);
        const int i = blockIdx.x * blockDim.x + threadIdx.x;
        float4 v = ((const float4*)lhs)[i];
        int b0 = q8(v.x, s), b1 = q8(v.y, s), b2 = q8(v.z, s), b3 = q8(v.w, s);
        ((int*)qA)[i] = (b0 & 0xff) | ((b1 & 0xff) << 8) | ((b2 & 0xff) << 16)
                      | ((b3 & 0xff) << 24);
    } else {
        const float s = 127.0f / fmaxf(__uint_as_float(amax[1]), 1e-12f);
        const int b = blockIdx.x - 16384;
        const int n0 = (b & 63) * 64, k0 = (b >> 6) * 64;
        const int rl = threadIdx.x >> 4;   // k row within 16-row slab
        const int nq = threadIdx.x & 15;   // float4 column
        for (int r = 0; r < 4; ++r) {
            const int kl = r * 16 + rl;
            float4 v = *(const float4*)(rhs + (size_t)(k0 + kl) * NROW + n0 + nq * 4);
            sm[nq * 4 + 0][kl] = (int8_t)q8(v.x, s);
            sm[nq * 4 + 1][kl] = (int8_t)q8(v.y, s);
            sm[nq * 4 + 2][kl] = (int8_t)q8(v.z, s);
            sm[nq * 4 + 3][kl] = (int8_t)q8(v.w, s);
        }
        __syncthreads();
        const int nl = threadIdx.x >> 2;
        const int kq = threadIdx.x & 3;
        int4 w;
        w.x = *(const int*)&sm[nl][kq * 16 + 0];
        w.y = *(const int*)&sm[nl][kq * 16 + 4];
        w.z = *(const int*)&sm[nl][kq * 16 + 8];
        w.w = *(const int*)&sm[nl][kq * 16 + 12];
        *(int4*)(qT + (size_t)(n0 + nl) * NROW + k0 + kq * 16) = w;
    }
}

// 128x128 tile, 4 waves (2Mx2N of 64x64), BK=64, double-buffered LDS (32 KiB
// -> 4 blocks/CU with VGPR<=128). Window w: [stage tile w+1 -> slot (w+1)&1
// (4 global_load_lds/thread); compute slot w&1 (8 ds_read_b128 + 16 MFMA);
// vmcnt(0) (loads are a full window old); s_barrier]. Cross-block wave
// interleaving on each CU overlaps this block's LDS phase with another
// block's MFMA phase. WAR safety: slot (w+1)&1 was last read in window w-1,
// which ended at a barrier before these writes are issued.
__global__ __launch_bounds__(256, 4) void gemm_i8_kernel(
    const int8_t* __restrict__ qA, const int8_t* __restrict__ qBT,
    float* __restrict__ out, const unsigned* __restrict__ amax) {
    __shared__ __align__(16) int8_t sA[2][128 * 64];
    __shared__ __align__(16) int8_t sB[2][128 * 64];

    const int tid = threadIdx.x;
    const int lane = tid & 63;
    const int wave = tid >> 6;      // 0..3
    const int wm = wave >> 1;       // 0..1 : 64-row sub-tile
    const int wn = wave & 1;        // 0..1 : 64-col sub-tile

    // XCD-aware bijective swizzle (grid 1024, 1024%8==0): XCD k gets swz ids
    // [128k,128k+128) -> 4 contiguous M-panels (2 MB of A) reused across its
    // 32 N-tiles; L3 holds both 16 MB tensors so HBM refetch stays low.
    const int bid = blockIdx.y * 32 + blockIdx.x;
    const int swz = (bid & 7) * 128 + (bid >> 3);
    const int m0 = (swz >> 5) * 128, n0 = (swz & 31) * 128;

    const int r = lane & 15;        // row/col within 16
    const int q = lane >> 4;        // K-quad (16 B) within 64

    // Frag read offsets. Pos = (q + (row>>1)) & 3 is invariant across mi/ni
    // (row steps by 16 -> row>>1 by 8 == 0 mod 4): mi/ni folds into the
    // ds_read immediate (+1024 per 16 rows).
    const int rowA = wm * 64 + r;
    const int aoff = rowA * 64 + ((q + (rowA >> 1)) & 3) * 16;
    const int rowB = wn * 64 + r;
    const int boff = rowB * 64 + ((q + (rowB >> 1)) & 3) * 16;

    // Staging: 512 16B-chunks per tensor per K-tile (128 rows x 4 quads),
    // 2 per thread per tensor. Linear LDS destination; global source quad
    // inverse-swizzled: chunk c -> row c>>2, pos c&3 holds quad ((c&3)-(row>>1))&3.
    gptr1_t pA[2], pB[2];
    int dstc[2];
#pragma unroll
    for (int j = 0; j < 2; ++j) {
        const int c = tid + j * 256;
        const int row = c >> 2;
        const int G = ((c & 3) - (row >> 1)) & 3;
        pA[j] = (gptr1_t)(qA + (size_t)(m0 + row) * NROW + G * 16);
        pB[j] = (gptr1_t)(qBT + (size_t)(n0 + row) * NROW + G * 16);
        dstc[j] = c * 16;
    }
    int8_t* sAf = &sA[0][0];
    int8_t* sBf = &sB[0][0];

    auto stage = [&](int slot, int kb) {
#pragma unroll
        for (int j = 0; j < 2; ++j) {
            __builtin_amdgcn_global_load_lds(
                pA[j] + kb, (lptr3_t)(sAf + slot * 8192 + dstc[j]), 16, 0, 0);
            __builtin_amdgcn_global_load_lds(
                pB[j] + kb, (lptr3_t)(sBf + slot * 8192 + dstc[j]), 16, 0, 0);
        }
    };

    int32x4 acc[4][4];
#pragma unroll
    for (int mi = 0; mi < 4; ++mi)
#pragma unroll
        for (int ni = 0; ni < 4; ++ni) acc[mi][ni] = (int32x4)(0);

    auto compute = [&](const int8_t* a, const int8_t* b) {
        int32x4 af[4], bf[4];
#pragma unroll
        for (int mi = 0; mi < 4; ++mi)
            af[mi] = *(const int32x4*)(a + aoff + mi * 1024);
#pragma unroll
        for (int ni = 0; ni < 4; ++ni)
            bf[ni] = *(const int32x4*)(b + boff + ni * 1024);
        __builtin_amdgcn_s_setprio(1);
#pragma unroll
        for (int mi = 0; mi < 4; ++mi)
#pragma unroll
            for (int ni = 0; ni < 4; ++ni)
                acc[mi][ni] = __builtin_amdgcn_mfma_i32_16x16x64_i8(
                    af[mi], bf[ni], acc[mi][ni], 0, 0, 0);
        __builtin_amdgcn_s_setprio(0);
    };

    // Prologue: stage tile 0 into slot 0; drain; barrier.
    stage(0, 0);
    asm volatile("s_waitcnt vmcnt(0)" ::: "memory");
    __builtin_amdgcn_sched_barrier(0);
    __builtin_amdgcn_s_barrier();
    __builtin_amdgcn_sched_barrier(0);

    // 64 K-tiles of 64. Windows 0..62 stage the next tile; window 63 below.
#pragma unroll 1
    for (int w = 0; w < 63; ++w) {
        stage((w + 1) & 1, (w + 1) * 64);
        compute(sAf + (w & 1) * 8192, sBf + (w & 1) * 8192);
        asm volatile("s_waitcnt vmcnt(0)" ::: "memory");
        __builtin_amdgcn_sched_barrier(0);
        __builtin_amdgcn_s_barrier();
        __builtin_amdgcn_sched_barrier(0);
    }
    compute(sAf + 8192, sBf + 8192);  // tile 63, slot 1

    // Epilogue: dequant + store. C/D layout: col = lane&15, row = (lane>>4)*4+reg
    const float ls = 127.0f / fmaxf(__uint_as_float(amax[0]), 1e-12f);
    const float rs = 127.0f / fmaxf(__uint_as_float(amax[1]), 1e-12f);
    const float inv = 1.0f / (ls * rs);
#pragma unroll
    for (int mi = 0; mi < 4; ++mi)
#pragma unroll
        for (int ni = 0; ni < 4; ++ni)
#pragma unroll
            for (int reg = 0; reg < 4; ++reg) {
                const int row = m0 + wm * 64 + mi * 16 + q * 4 + reg;
                const int col = n0 + wn * 64 + ni * 16 + r;
                out[(size_t)row * NROW + col] = (float)acc[mi][ni][reg] * inv;
            }
}

extern "C" void kernel_launch(void* const* d_in, const int* in_sizes, int n_in,
                              void* d_out, int out_size, void* d_ws,
                              size_t ws_size, hipStream_t stream) {
    const float* lhs = (const float*)d_in[0];
    const float* rhs = (const float*)d_in[1];
    float* out = (float*)d_out;

    int8_t* qA = (int8_t*)d_ws;
    int8_t* qBT = qA + (size_t)16 * 1024 * 1024;
    unsigned* amax = (unsigned*)(qBT + (size_t)16 * 1024 * 1024);

    hipMemsetAsync(amax, 0, 8, stream);
    absmax_both_kernel<<<2048, 256, 0, stream>>>(lhs, rhs, amax);
    quant_kernel<<<16384 + 4096, 256, 0, stream>>>(lhs, rhs, qA, qBT, amax);
    gemm_i8_kernel<<<dim3(32, 32), 256, 0, stream>>>(qA, qBT, out, amax);
}

// Round 9
// 141.004 us; speedup vs baseline: 1.0638x; 1.0638x over previous
//
#include <hip/hip_runtime.h>
#include <stdint.h>

// out = dequant( int8(lhs*ls) @ int8(rhs*rs) ) / (ls*rs), 4096^3, fp32 in/out.
// ls = 127 / max(amax|lhs|, 1e-12). Int core is bit-exact vs numpy (RNE quant).
//
// Workspace: [0,16Mi) qA int8 MxK ; [16Mi,32Mi) qBT int8 NxK ; then 2x u32 amax bits.
//
// GEMM v8 = v6 (best known: 83 us, BK=128 windows, 256x256 tile, 8 waves of
// 128x64, double-buffered LDS, prefetch-1, one barrier/window) with the MFMA
// swapped 16x16x64 -> 32x32x32: +12% pipe rate (4404 vs 3944 TOPS ubench) and
// half the MFMA instruction count per window (32 vs 64) at identical LDS
// traffic (reads depend only on wave-tile geometry: 24 ds_read_b128/wave).
// acc = 4x2 tiles x 16 regs = 128 VGPRs (v6's exact register shape).
// Frag layout (32x32x32 i8): lane l holds A[row=l&31][k=(l>>5)*16+j] -- a
// contiguous 16 B read from row-major [row][K] LDS, global quad
// g = 2*ks + (l>>5); same for B from qBT. C/D: col=lane&31,
// row=(reg&3)+8*(reg>>2)+4*(lane>>5) (HW-verified, dtype-independent).
// Swizzle: v6's verified 128B-row scheme -- LDS pos p of row r holds global
// quad (p-r)&7; read pos (g+r)&7; 8-lane groups cover all 32 banks exactly.

#define NROW 4096
#define NELEM (4096 * 4096)

typedef __attribute__((ext_vector_type(4))) int int32x4;
typedef __attribute__((ext_vector_type(16))) int int32x16;
typedef const __attribute__((address_space(1))) int8_t* gptr1_t;
typedef __attribute__((address_space(3))) int8_t* lptr3_t;

__global__ void absmax_both_kernel(const float* __restrict__ lhs,
                                   const float* __restrict__ rhs,
                                   unsigned* __restrict__ amax) {
    __shared__ float red[4];
    const int t = blockIdx.x & 1;
    const float4* x4 = (const float4*)(t ? rhs : lhs);
    const int bid = blockIdx.x >> 1;
    const int stride = (gridDim.x >> 1) * blockDim.x;  // 262144
    int i = bid * blockDim.x + threadIdx.x;
    float m0 = 0.0f, m1 = 0.0f, m2 = 0.0f, m3 = 0.0f;
    for (; i + 3 * stride < NELEM / 4; i += 4 * stride) {
        float4 a = x4[i];
        float4 b = x4[i + stride];
        float4 c = x4[i + 2 * stride];
        float4 d = x4[i + 3 * stride];
        m0 = fmaxf(m0, fmaxf(fmaxf(fabsf(a.x), fabsf(a.y)),
                             fmaxf(fabsf(a.z), fabsf(a.w))));
        m1 = fmaxf(m1, fmaxf(fmaxf(fabsf(b.x), fabsf(b.y)),
                             fmaxf(fabsf(b.z), fabsf(b.w))));
        m2 = fmaxf(m2, fmaxf(fmaxf(fabsf(c.x), fabsf(c.y)),
                             fmaxf(fabsf(c.z), fabsf(c.w))));
        m3 = fmaxf(m3, fmaxf(fmaxf(fabsf(d.x), fabsf(d.y)),
                             fmaxf(fabsf(d.z), fabsf(d.w))));
    }
    for (; i < NELEM / 4; i += stride) {
        float4 a = x4[i];
        m0 = fmaxf(m0, fmaxf(fmaxf(fabsf(a.x), fabsf(a.y)),
                             fmaxf(fabsf(a.z), fabsf(a.w))));
    }
    float m = fmaxf(fmaxf(m0, m1), fmaxf(m2, m3));
    for (int off = 32; off > 0; off >>= 1)
        m = fmaxf(m, __shfl_down(m, off, 64));
    const int lane = threadIdx.x & 63, wave = threadIdx.x >> 6;
    if (lane == 0) red[wave] = m;
    __syncthreads();
    if (threadIdx.x == 0) {
        float b = fmaxf(fmaxf(red[0], red[1]), fmaxf(red[2], red[3]));
        atomicMax(amax + t, __float_as_uint(b));  // |x|>=0: bits monotone as uint
    }
}

__device__ __forceinline__ int q8(float v, float s) {
    int r = __float2int_rn(v * s);  // RNE, matches jnp.round
    r = r < -127 ? -127 : r;
    r = r > 127 ? 127 : r;
    return r;
}

__global__ void quant_kernel(const float* __restrict__ lhs,
                             const float* __restrict__ rhs,
                             int8_t* __restrict__ qA, int8_t* __restrict__ qT,
                             const unsigned* __restrict__ amax) {
    __shared__ int8_t sm[64][68];
    if (blockIdx.x < 16384) {
        const float s = 127.0f / fmaxf(__uint_as_float(amax[0]), 1e-12f);
        const int i = blockIdx.x * blockDim.x + threadIdx.x;
        float4 v = ((const float4*)lhs)[i];
        int b0 = q8(v.x, s), b1 = q8(v.y, s), b2 = q8(v.z, s), b3 = q8(v.w, s);
        ((int*)qA)[i] = (b0 & 0xff) | ((b1 & 0xff) << 8) | ((b2 & 0xff) << 16)
                      | ((b3 & 0xff) << 24);
    } else {
        const float s = 127.0f / fmaxf(__uint_as_float(amax[1]), 1e-12f);
        const int b = blockIdx.x - 16384;
        const int n0 = (b & 63) * 64, k0 = (b >> 6) * 64;
        const int rl = threadIdx.x >> 4;   // k row within 16-row slab
        const int nq = threadIdx.x & 15;   // float4 column
        for (int r = 0; r < 4; ++r) {
            const int kl = r * 16 + rl;
            float4 v = *(const float4*)(rhs + (size_t)(k0 + kl) * NROW + n0 + nq * 4);
            sm[nq * 4 + 0][kl] = (int8_t)q8(v.x, s);
            sm[nq * 4 + 1][kl] = (int8_t)q8(v.y, s);
            sm[nq * 4 + 2][kl] = (int8_t)q8(v.z, s);
            sm[nq * 4 + 3][kl] = (int8_t)q8(v.w, s);
        }
        __syncthreads();
        const int nl = threadIdx.x >> 2;
        const int kq = threadIdx.x & 3;
        int4 w;
        w.x = *(const int*)&sm[nl][kq * 16 + 0];
        w.y = *(const int*)&sm[nl][kq * 16 + 4];
        w.z = *(const int*)&sm[nl][kq * 16 + 8];
        w.w = *(const int*)&sm[nl][kq * 16 + 12];
        *(int4*)(qT + (size_t)(n0 + nl) * NROW + k0 + kq * 16) = w;
    }
}

// 256x256 tile, 8 waves (wave-tile 128x64 = 4x2 of 32x32), BK=128, double-
// buffered LDS. Window w: [stage tile w+1 -> slot (w+1)&1 (8 gload_lds/thr);
// compute slot w&1 (4 ks-slices x {6 ds_read_b128 + 8 mfma_i32_32x32x32_i8});
// vmcnt(0) (loads are a full window old -- no stall); s_barrier]. WAR safety:
// slot (w+1)&1 was last read in window w-1, which ended at a barrier.
__global__ __launch_bounds__(512, 2) void gemm_i8_kernel(
    const int8_t* __restrict__ qA, const int8_t* __restrict__ qBT,
    float* __restrict__ out, const unsigned* __restrict__ amax) {
    __shared__ __align__(16) int8_t sA[2][256 * 128];
    __shared__ __align__(16) int8_t sB[2][256 * 128];

    const int tid = threadIdx.x;
    const int lane = tid & 63;
    const int wave = tid >> 6;      // 0..7
    const int wm = wave >> 2;       // 0..1 : 128-row sub-tile
    const int wn = wave & 3;        // 0..3 : 64-col sub-tile

    // XCD-aware bijective swizzle (grid 256, 256%8==0): XCD k gets swz ids
    // [32k,32k+32) -> 2 contiguous M-rows: A-panels L2-resident per XCD.
    const int bid = blockIdx.y * 16 + blockIdx.x;
    const int swz = (bid & 7) * 32 + (bid >> 3);
    const int m0 = (swz >> 4) * 256, n0 = (swz & 15) * 256;

    const int rl = lane & 31;       // row within a 32-row MFMA tile
    const int hi = lane >> 5;       // k-half selector (16 B granule)

    // Frag read offsets. Global quad for k-slice ks: g = 2*ks + hi; LDS pos
    // = (g + row) & 7 (staging stores pos p <- quad (p - row) & 7). Row
    // steps of 32 (mt/nt) are 0 mod 8 -> pos invariant; they fold into the
    // ds_read immediate (+4096 per 32 rows).
    const int rowA = wm * 128 + rl;
    const int rowB = wn * 64 + rl;
    int aoff4[4], boff4[4];
#pragma unroll
    for (int ks = 0; ks < 4; ++ks) {
        aoff4[ks] = rowA * 128 + (((2 * ks + hi + rowA) & 7) << 4);
        boff4[ks] = rowB * 128 + (((2 * ks + hi + rowB) & 7) << 4);
    }

    // Staging: 2048 16B-chunks per tensor per K-tile (256 rows x 8 quads),
    // 4 per thread. Linear LDS destination (global_load_lds requirement);
    // global source quad inverse-swizzled: chunk c -> row c>>3, pos c&7
    // holds global quad ((c&7) - row) & 7.
    gptr1_t pA[4], pB[4];
#pragma unroll
    for (int j = 0; j < 4; ++j) {
        const int c = tid + j * 512;
        const int row = c >> 3;
        const int G = ((c & 7) - row) & 7;
        pA[j] = (gptr1_t)(qA + (size_t)(m0 + row) * NROW + G * 16);
        pB[j] = (gptr1_t)(qBT + (size_t)(n0 + row) * NROW + G * 16);
    }
    int8_t* sAf = &sA[0][0];
    int8_t* sBf = &sB[0][0];
    const int dst0 = tid * 16;

    auto stage = [&](int slot, int kb) {
#pragma unroll
        for (int j = 0; j < 4; ++j) {
            __builtin_amdgcn_global_load_lds(
                pA[j] + kb, (lptr3_t)(sAf + slot * 32768 + dst0 + j * 8192),
                16, 0, 0);
            __builtin_amdgcn_global_load_lds(
                pB[j] + kb, (lptr3_t)(sBf + slot * 32768 + dst0 + j * 8192),
                16, 0, 0);
        }
    };

    int32x16 acc[4][2];
#pragma unroll
    for (int mt = 0; mt < 4; ++mt)
#pragma unroll
        for (int nt = 0; nt < 2; ++nt) acc[mt][nt] = (int32x16)(0);

    auto compute = [&](const int8_t* a, const int8_t* b) {
#pragma unroll
        for (int ks = 0; ks < 4; ++ks) {
            int32x4 af[4], bf[2];
#pragma unroll
            for (int mt = 0; mt < 4; ++mt)
                af[mt] = *(const int32x4*)(a + aoff4[ks] + mt * 4096);
#pragma unroll
            for (int nt = 0; nt < 2; ++nt)
                bf[nt] = *(const int32x4*)(b + boff4[ks] + nt * 4096);
            __builtin_amdgcn_s_setprio(1);
#pragma unroll
            for (int mt = 0; mt < 4; ++mt)
#pragma unroll
                for (int nt = 0; nt < 2; ++nt)
                    acc[mt][nt] = __builtin_amdgcn_mfma_i32_32x32x32_i8(
                        af[mt], bf[nt], acc[mt][nt], 0, 0, 0);
            __builtin_amdgcn_s_setprio(0);
        }
    };

    // Prologue: stage tile 0 into slot 0; drain; barrier.
    stage(0, 0);
    asm volatile("s_waitcnt vmcnt(0)" ::: "memory");
    __builtin_amdgcn_sched_barrier(0);
    __builtin_amdgcn_s_barrier();
    __builtin_amdgcn_sched_barrier(0);

    // 32 K-tiles of 128. Windows 0..30 stage the next tile; window 31 below.
#pragma unroll 1
    for (int w = 0; w < 31; ++w) {
        stage((w + 1) & 1, (w + 1) * 128);
        compute(sAf + (w & 1) * 32768, sBf + (w & 1) * 32768);
        asm volatile("s_waitcnt vmcnt(0)" ::: "memory");
        __builtin_amdgcn_sched_barrier(0);
        __builtin_amdgcn_s_barrier();
        __builtin_amdgcn_sched_barrier(0);
    }
    compute(sAf + 32768, sBf + 32768);  // tile 31, slot 1

    // Epilogue: dequant + store. 32x32 C/D layout: col = lane&31,
    // row = (reg&3) + 8*(reg>>2) + 4*(lane>>5).
    const float ls = 127.0f / fmaxf(__uint_as_float(amax[0]), 1e-12f);
    const float rs = 127.0f / fmaxf(__uint_as_float(amax[1]), 1e-12f);
    const float inv = 1.0f / (ls * rs);
#pragma unroll
    for (int mt = 0; mt < 4; ++mt)
#pragma unroll
        for (int nt = 0; nt < 2; ++nt)
#pragma unroll
            for (int reg = 0; reg < 16; ++reg) {
                const int row = m0 + wm * 128 + mt * 32 + (reg & 3) +
                                8 * (reg >> 2) + 4 * hi;
                const int col = n0 + wn * 64 + nt * 32 + rl;
                out[(size_t)row * NROW + col] = (float)acc[mt][nt][reg] * inv;
            }
}

extern "C" void kernel_launch(void* const* d_in, const int* in_sizes, int n_in,
                              void* d_out, int out_size, void* d_ws,
                              size_t ws_size, hipStream_t stream) {
    const float* lhs = (const float*)d_in[0];
    const float* rhs = (const float*)d_in[1];
    float* out = (float*)d_out;

    int8_t* qA = (int8_t*)d_ws;
    int8_t* qBT = qA + (size_t)16 * 1024 * 1024;
    unsigned* amax = (unsigned*)(qBT + (size_t)16 * 1024 * 1024);

    hipMemsetAsync(amax, 0, 8, stream);
    absmax_both_kernel<<<2048, 256, 0, stream>>>(lhs, rhs, amax);
    quant_kernel<<<16384 + 4096, 256, 0, stream>>>(lhs, rhs, qA, qBT, amax);
    gemm_i8_kernel<<<dim3(16, 16), 512, 0, stream>>>(qA, qBT, out, amax);
}